// Round 11
// baseline (53.711 us; speedup 1.0000x reference)
//
#include <hip/hip_runtime.h>
#include <math.h>

#define N 64
#define PLANE 4096
#define MASK1 0x17u              // labels {0,1,2,4} (pair 1)
#define MASK2 0x13u              // labels {0,1,4}   (pair 2)
#define SENT 16000               // i16 sentinel (exactness: r9/r10, absmax 0)
typedef unsigned long long ull;

// ---------------------------------------------------------------------------
// Workspace (bytes):
//   CX_OFF: ull cx[4][4096] — y-column occupancy masks, mi = m*2+b (128 KB)
//   PART_OFF: float part[256][8]; CTR_OFF: int ctr[2] (memset each call)
//     ctr[0] = grid barrier, ctr[1] = last-block counter
// Block bid: part 1 -> plane p=bid>>1 (b=p>>6, x=p&63), y-half h=bid&1.
//            part 2 -> mi=bid>>6 (m=bid>>7), y0=bid&63.
//   m=0: tsd1 x bnd2 -> h_outer; m=1: tsd2 x bnd1 -> h_inner.
// ---------------------------------------------------------------------------
#define CX_OFF ((size_t)0)
#define PART_OFF ((size_t)131072)
#define CTR_OFF (PART_OFF + (size_t)256 * 8 * 4)

__global__ __launch_bounds__(512) void hausdorff_one(
    const int* __restrict__ mmap, void* __restrict__ wsv,
    float* __restrict__ out) {
  __shared__ ull cxO[4096];              // own-mask columns (32 KB)
  __shared__ ull cxP[4096];              // partner columns; phase B+: g2p alias
  __shared__ unsigned g1p[64][65];       // [x][z] {i16 T | i16 L<<16}, +z^2
  __shared__ unsigned char colb[2][8][64];
  __shared__ ull bndCol[64];             // partner bnd bits at y0, per x (bit z)
  __shared__ float redS[8], redB[8], redM[8];
  __shared__ int lastFlag;

  const int bid = blockIdx.x;
  const int t = threadIdx.x;
  const int z = t & 63;                  // == lane id (512t = 8 waves of 64)
  ull* cxg = (ull*)((char*)wsv + CX_OFF);
  int* ctr = (int*)((char*)wsv + CTR_OFF);

  // ================= PART 1: binarize mmap -> cx bit-volume =================
  {
    const int p = bid >> 1, h = bid & 1;  // plane p = b*64+x, y-half h
    const int c = t >> 6;                 // y-chunk: y = 32h + 4c + k
    const size_t pb = (size_t)p * PLANE;
    unsigned n1 = 0, n2 = 0;
    #pragma unroll
    for (int k = 0; k < 4; ++k) {
      const int v = mmap[pb + (32 * h + 4 * c + k) * N + z];
      n1 |= ((MASK1 >> v) & 1u) << k;
      n2 |= ((MASK2 >> v) & 1u) << k;
    }
    colb[0][c][z] = (unsigned char)n1;
    colb[1][c][z] = (unsigned char)n2;
    __syncthreads();
    if (t < 128) {
      const int mm = t >> 6, zz = t & 63;
      unsigned half = 0;
      #pragma unroll
      for (int cc = 0; cc < 8; ++cc)
        half |= (unsigned)colb[mm][cc][zz] << (4 * cc);
      const int b = p >> 6, x = p & 63;
      ((unsigned*)cxg)[((size_t)(mm * 2 + b) * 4096 + x * 64 + zz) * 2 + h] =
          half;
    }
  }

  // ===================== GRID BARRIER (256 blocks) ==========================
  __syncthreads();
  if (t == 0) {
    __threadfence();                      // release cx halves device-scope
    atomicAdd(&ctr[0], 1);
    while (__hip_atomic_load(&ctr[0], __ATOMIC_ACQUIRE,
                             __HIP_MEMORY_SCOPE_AGENT) < 256) {
      __builtin_amdgcn_s_sleep(2);
    }
    __threadfence();                      // acquire
  }
  __syncthreads();

  // ================= PART 2: EDT at plane (m, b, y0) ========================
  const int m = bid >> 7;
  const int mi = bid >> 6;                // m*2+b
  const int y0 = bid & 63;
  const int miP = ((1 - m) << 1) | (mi & 1);

  // stage cx columns (own + partner) into LDS; L3/L2-resident after barrier
  #pragma unroll
  for (int k = 0; k < 8; ++k) {
    const int ci = t + 512 * k;
    cxO[ci] = cxg[(size_t)mi * 4096 + ci];
    cxP[ci] = cxg[(size_t)miP * 4096 + ci];
  }
  __syncthreads();

  // ---- phase A: in-LDS stencil + Y-distances at y0 + partner bnd bits ----
  #pragma unroll
  for (int k = 0; k < 8; ++k) {
    const int ci = t + 512 * k;
    const int x = ci >> 6;                // z == t&63 (lane)
    const ull c0 = cxO[ci];
    const ull xm = (x > 0) ? cxO[ci - 64] : 0ull;
    const ull xp = (x < 63) ? cxO[ci + 64] : 0ull;
    const ull zm = (z > 0) ? cxO[ci - 1] : 0ull;
    const ull zp = (z < 63) ? cxO[ci + 1] : 0ull;
    const ull nb = xm | xp | zm | zp | (c0 << 1) | (c0 >> 1);
    const ull mT = ~c0;                   // tdm zero-set
    const ull mLw = c0 | nb;              // levelzero zero-set
    const int zs = z * z;
    unsigned vT, vL;
    {
      const ull hi = mT >> y0;
      const int du = hi ? (__ffsll((long long)hi) - 1) : 99;
      const int dd = (int)__clzll((long long)(mT << (63 - y0)));
      const int d = min(du, dd);
      vT = (d > 63) ? (unsigned)SENT : (unsigned)(d * d + zs);
    }
    {
      const ull hi = mLw >> y0;
      const int du = hi ? (__ffsll((long long)hi) - 1) : 99;
      const int dd = (int)__clzll((long long)(mLw << (63 - y0)));
      const int d = min(du, dd);
      vL = (d > 63) ? (unsigned)SENT : (unsigned)(d * d + zs);
    }
    g1p[x][z] = vT | (vL << 16);
    // partner boundary bit at y0: dilate(cxP) & ~cxP
    const ull p0 = cxP[ci];
    const ull pxm = (x > 0) ? cxP[ci - 64] : 0ull;
    const ull pxp = (x < 63) ? cxP[ci + 64] : 0ull;
    const ull pzm = (z > 0) ? cxP[ci - 1] : 0ull;
    const ull pzp = (z < 63) ? cxP[ci + 1] : 0ull;
    const ull pnb = pxm | pxp | pzm | pzp | (p0 << 1) | (p0 >> 1);
    const int bit = (int)(((pnb & ~p0) >> y0) & 1ull);
    const ull bal = __ballot(bit);        // lane == z: bit z of bndCol[x]
    if (z == 0) bndCol[x] = bal;
  }
  __syncthreads();

  unsigned* g2p = (unsigned*)cxP;         // [z'][x] stride 67, overlays cxP

  // ---- phase B: Z-envelope, packed i16. x=t>>3, outputs z'=g+8q. ----
  {
    const int x = t >> 3, g = t & 7;
    unsigned acc[8], n2i[8];
    #pragma unroll
    for (int q = 0; q < 8; ++q) {
      acc[q] = 0x7FFF7FFFu;
      n2i[q] = (unsigned)(unsigned short)(-2 * (g + 8 * q)) * 0x10001u;
    }
    unsigned jp = 0;                      // packed {j, j}
    const unsigned* row = &g1p[x][0];
    #pragma unroll 4
    for (int j = 0; j < 64; ++j) {
      const unsigned fj = row[j];
      #pragma unroll
      for (int q = 0; q < 8; ++q) {
        unsigned d;
        asm("v_pk_mad_i16 %0, %1, %2, %3"
            : "=v"(d) : "v"(n2i[q]), "v"(jp), "v"(fj));
        asm("v_pk_min_i16 %0, %1, %2" : "=v"(acc[q]) : "v"(acc[q]), "v"(d));
      }
      jp += 0x10001u;
    }
    const int xs = x * x;
    #pragma unroll
    for (int q = 0; q < 8; ++q) {
      const int zpr = g + 8 * q;
      const unsigned spk = (unsigned)(zpr * zpr + xs) * 0x10001u;
      unsigned gv;
      asm("v_pk_add_i16 %0, %1, %2" : "=v"(gv) : "v"(acc[q]), "v"(spk));
      g2p[zpr * 67 + x] = gv;             // transposed store
    }
  }
  __syncthreads();

  // ---- phase C: X-envelope + epilogue. z=t>>3, outputs x'=g+8q. ----
  {
    const int zc = t >> 3, g = t & 7;
    unsigned acc[8], n2i[8];
    #pragma unroll
    for (int q = 0; q < 8; ++q) {
      acc[q] = 0x7FFF7FFFu;
      n2i[q] = (unsigned)(unsigned short)(-2 * (g + 8 * q)) * 0x10001u;
    }
    unsigned jp = 0;
    const unsigned* row = &g2p[zc * 67];
    #pragma unroll 4
    for (int j = 0; j < 64; ++j) {
      const unsigned fj = row[j];
      #pragma unroll
      for (int q = 0; q < 8; ++q) {
        unsigned d;
        asm("v_pk_mad_i16 %0, %1, %2, %3"
            : "=v"(d) : "v"(n2i[q]), "v"(jp), "v"(fj));
        asm("v_pk_min_i16 %0, %1, %2" : "=v"(acc[q]) : "v"(acc[q]), "v"(d));
      }
      jp += 0x10001u;
    }
    float hsum = 0.f, bsum = 0.f, hmax = 0.f;
    #pragma unroll
    for (int q = 0; q < 8; ++q) {
      const int xpr = g + 8 * q;
      const int xs2 = xpr * xpr;
      const int eT = (int)(short)(acc[q] & 0xFFFFu) + xs2;
      const int eL = (int)(short)(acc[q] >> 16) + xs2;
      const float tsd = sqrtf((float)eT) - sqrtf((float)eL);
      const float bnd = (float)((bndCol[xpr] >> zc) & 1ull);
      const float h = bnd * fabsf(tsd);
      hsum += h; bsum += bnd; hmax = fmaxf(hmax, h);
    }
    #pragma unroll
    for (int o = 32; o > 0; o >>= 1) {
      hsum += __shfl_down(hsum, o);
      bsum += __shfl_down(bsum, o);
      hmax = fmaxf(hmax, __shfl_down(hmax, o));
    }
    const int w = t >> 6;
    if ((t & 63) == 0) { redS[w] = hsum; redB[w] = bsum; redM[w] = hmax; }
  }
  __syncthreads();

  // ---- per-block partials + last-block final reduction ----
  float* part = (float*)((char*)wsv + PART_OFF);
  if (t == 0) {
    float s = 0.f, bs = 0.f, mx = 0.f;
    #pragma unroll
    for (int i = 0; i < 8; ++i) {
      s += redS[i]; bs += redB[i]; mx = fmaxf(mx, redM[i]);
    }
    float* pp = part + (size_t)bid * 8;
    pp[0] = s; pp[1] = bs; pp[2] = mx;
    __threadfence();
    const int old = atomicAdd(&ctr[1], 1);
    lastFlag = (old == 255) ? 1 : 0;
  }
  __syncthreads();
  if (lastFlag) {
    __threadfence();  // acquire other blocks' partials
    float s = 0.f, bs = 0.f, mx = 0.f;
    if (t < 256) {
      const float* pp = part + (size_t)t * 8;
      s = pp[0]; bs = pp[1]; mx = pp[2];
    }
    #pragma unroll
    for (int o = 32; o > 0; o >>= 1) {
      s += __shfl_down(s, o);
      bs += __shfl_down(bs, o);
      mx = fmaxf(mx, __shfl_down(mx, o));
    }
    __syncthreads();
    if ((t & 63) == 0 && t < 256) {
      redS[t >> 6] = s; redB[t >> 6] = bs; redM[t >> 6] = mx;
    }
    __syncthreads();
    if (t == 0) {
      // partials p<128 are m=0: h_outer + bnd2; p>=128: h_inner + bnd1
      const float s_ho = redS[0] + redS[1], b2 = redB[0] + redB[1];
      const float mho = fmaxf(redM[0], redM[1]);
      const float s_hi = redS[2] + redS[3], b1 = redB[2] + redB[3];
      const float mhi = fmaxf(redM[2], redM[3]);
      const float him = s_hi / b1;
      const float hom = s_ho / b2;
      out[0] = him;
      out[1] = mhi;
      out[2] = hom;
      out[3] = mho;
      out[4] = (him - 2.f) * (him - 2.f) + (hom - 2.f) * (hom - 2.f);
    }
  }
}

extern "C" void kernel_launch(void* const* d_in, const int* in_sizes, int n_in,
                              void* d_out, int out_size, void* d_ws,
                              size_t ws_size, hipStream_t stream) {
  (void)in_sizes; (void)n_in; (void)out_size; (void)ws_size;
  const int* mmap = (const int*)d_in[0];
  float* out = (float*)d_out;

  hipMemsetAsync((char*)d_ws + CTR_OFF, 0, 8, stream);
  hausdorff_one<<<256, 512, 0, stream>>>(mmap, d_ws, out);
}

// Round 12
// 34.020 us; speedup vs baseline: 1.5788x; 1.5788x over previous
//
#include <hip/hip_runtime.h>
#include <math.h>

#define N 64
#define PLANE 4096
#define MASK1 0x17u              // labels {0,1,2,4} (pair 1)
#define MASK2 0x13u              // labels {0,1,4}   (pair 2)
#define SENT 16000               // i16 sentinel (exactness proven r9/r10, absmax 0)
typedef unsigned long long ull;

// ---------------------------------------------------------------------------
// Workspace (bytes):
//   CX_OFF: ull cx[4][4096] — y-column occupancy masks, mi = m*2+b (128 KB)
//   PART_OFF: float part[256][8] — per-edt_all-block partials
//   CTR_OFF: int ctr[2] — last-block counter (zeroed by build_bits)
// edt_all block bid: mi=bid>>6 (m=bid>>7, b=(bid>>6)&1), y0=bid&63.
//   m=0: tsd1 x bnd2 -> h_outer; m=1: tsd2 x bnd1 -> h_inner.
// ---------------------------------------------------------------------------
#define CX_OFF ((size_t)0)
#define PART_OFF ((size_t)131072)
#define CTR_OFF (PART_OFF + (size_t)256 * 8 * 4)

// K1: binarize mmap -> y-column bitmasks; zero the completion counter.
__global__ __launch_bounds__(512) void build_bits(const int* __restrict__ mmap,
                                                  void* __restrict__ wsv) {
  __shared__ unsigned char colb[2][8][64];
  const int bid = blockIdx.x;       // b*64 + x
  const int b = bid >> 6, x = bid & 63;
  const int t = threadIdx.x;
  const int z = t & 63, c = t >> 6;
  if (bid == 0 && t < 2) ((int*)((char*)wsv + CTR_OFF))[t] = 0;
  const size_t pb = (size_t)(b * N + x) * PLANE;
  unsigned b1 = 0, b2 = 0;
  #pragma unroll
  for (int k = 0; k < 8; ++k) {
    const int v = mmap[pb + (8 * c + k) * N + z];
    b1 |= ((MASK1 >> v) & 1u) << k;
    b2 |= ((MASK2 >> v) & 1u) << k;
  }
  colb[0][c][z] = (unsigned char)b1;
  colb[1][c][z] = (unsigned char)b2;
  __syncthreads();
  if (t < 128) {
    const int mm = t >> 6, zz = t & 63;
    ull v = 0;
    #pragma unroll
    for (int cc = 0; cc < 8; ++cc)
      v |= (ull)colb[mm][cc][zz] << (8 * cc);
    ((ull*)((char*)wsv + CX_OFF))[(size_t)(mm * 2 + b) * 4096 + x * 64 + zz] = v;
  }
}

// K2: one block per (m,b,y0). cx staged to LDS; in-LDS stencil; Y-eval at y0;
// packed-i16 Z- and X-envelopes; ballot boundary bits; last-block reduction.
__global__ __launch_bounds__(512) void edt_all(void* __restrict__ wsv,
                                               float* __restrict__ out) {
  __shared__ ull cxO[4096];              // own-mask columns (32 KB)
  __shared__ ull cxP[4096];              // partner columns; phases B/C: g2p alias
  __shared__ unsigned g1p[64][65];       // [x][z] {i16 T | i16 L<<16}, +z^2
  __shared__ ull bndCol[64];             // partner bnd bits at y0, per x (bit z)
  __shared__ float redS[8], redB[8], redM[8];
  __shared__ int lastFlag;
  const int bid = blockIdx.x;            // (m*2+b)*64 + y0
  const int m = bid >> 7;
  const int mi = bid >> 6;               // m*2+b
  const int y0 = bid & 63;
  const int miP = ((1 - m) << 1) | (mi & 1);
  const int t = threadIdx.x;
  const int z = t & 63;                  // lane id (512t = 8 waves of 64)

  const ull* cxg = (const ull*)((char*)wsv + CX_OFF);
  #pragma unroll
  for (int k = 0; k < 8; ++k) {
    const int ci = t + 512 * k;
    cxO[ci] = cxg[(size_t)mi * 4096 + ci];
    cxP[ci] = cxg[(size_t)miP * 4096 + ci];
  }
  __syncthreads();

  // ---- phase A: in-LDS stencil + Y-distances at y0 + partner bnd bits ----
  #pragma unroll
  for (int k = 0; k < 8; ++k) {
    const int ci = t + 512 * k;
    const int x = ci >> 6;
    const ull c0 = cxO[ci];
    const ull xm = (x > 0) ? cxO[ci - 64] : 0ull;
    const ull xp = (x < 63) ? cxO[ci + 64] : 0ull;
    const ull zm = (z > 0) ? cxO[ci - 1] : 0ull;
    const ull zp = (z < 63) ? cxO[ci + 1] : 0ull;
    const ull nb = xm | xp | zm | zp | (c0 << 1) | (c0 >> 1);
    const ull mT = ~c0;                   // tdm zero-set
    const ull mLw = c0 | nb;              // levelzero zero-set
    const int zs = z * z;
    unsigned vT, vL;
    {
      const ull hi = mT >> y0;
      const int du = hi ? (__ffsll((long long)hi) - 1) : 99;
      const int dd = (int)__clzll((long long)(mT << (63 - y0)));
      const int d = min(du, dd);
      vT = (d > 63) ? (unsigned)SENT : (unsigned)(d * d + zs);
    }
    {
      const ull hi = mLw >> y0;
      const int du = hi ? (__ffsll((long long)hi) - 1) : 99;
      const int dd = (int)__clzll((long long)(mLw << (63 - y0)));
      const int d = min(du, dd);
      vL = (d > 63) ? (unsigned)SENT : (unsigned)(d * d + zs);
    }
    g1p[x][z] = vT | (vL << 16);
    // partner boundary bit at y0: dilate(cxP) & ~cxP
    const ull p0 = cxP[ci];
    const ull pxm = (x > 0) ? cxP[ci - 64] : 0ull;
    const ull pxp = (x < 63) ? cxP[ci + 64] : 0ull;
    const ull pzm = (z > 0) ? cxP[ci - 1] : 0ull;
    const ull pzp = (z < 63) ? cxP[ci + 1] : 0ull;
    const ull pnb = pxm | pxp | pzm | pzp | (p0 << 1) | (p0 >> 1);
    const int bit = (int)(((pnb & ~p0) >> y0) & 1ull);
    const ull bal = __ballot(bit);        // lane == z: bit z of bndCol[x]
    if (z == 0) bndCol[x] = bal;
  }
  __syncthreads();

  unsigned* g2p = (unsigned*)cxP;         // [z'][x] stride 67, overlays cxP

  // ---- phase B: Z-envelope, packed i16. x=t>>3, outputs z'=g+8q. ----
  {
    const int x = t >> 3, g = t & 7;
    unsigned acc[8], n2i[8];
    #pragma unroll
    for (int q = 0; q < 8; ++q) {
      acc[q] = 0x7FFF7FFFu;
      n2i[q] = (unsigned)(unsigned short)(-2 * (g + 8 * q)) * 0x10001u;
    }
    unsigned jp = 0;                      // packed {j, j}
    const unsigned* row = &g1p[x][0];
    #pragma unroll 4
    for (int j = 0; j < 64; ++j) {
      const unsigned fj = row[j];
      #pragma unroll
      for (int q = 0; q < 8; ++q) {
        unsigned d;
        asm("v_pk_mad_i16 %0, %1, %2, %3"
            : "=v"(d) : "v"(n2i[q]), "v"(jp), "v"(fj));
        asm("v_pk_min_i16 %0, %1, %2" : "=v"(acc[q]) : "v"(acc[q]), "v"(d));
      }
      jp += 0x10001u;
    }
    const int xs = x * x;
    #pragma unroll
    for (int q = 0; q < 8; ++q) {
      const int zpr = g + 8 * q;
      const unsigned spk = (unsigned)(zpr * zpr + xs) * 0x10001u;
      unsigned gv;
      asm("v_pk_add_i16 %0, %1, %2" : "=v"(gv) : "v"(acc[q]), "v"(spk));
      g2p[zpr * 67 + x] = gv;             // transposed store
    }
  }
  __syncthreads();

  // ---- phase C: X-envelope + epilogue. z=t>>3, outputs x'=g+8q. ----
  {
    const int zc = t >> 3, g = t & 7;
    unsigned acc[8], n2i[8];
    #pragma unroll
    for (int q = 0; q < 8; ++q) {
      acc[q] = 0x7FFF7FFFu;
      n2i[q] = (unsigned)(unsigned short)(-2 * (g + 8 * q)) * 0x10001u;
    }
    unsigned jp = 0;
    const unsigned* row = &g2p[zc * 67];
    #pragma unroll 4
    for (int j = 0; j < 64; ++j) {
      const unsigned fj = row[j];
      #pragma unroll
      for (int q = 0; q < 8; ++q) {
        unsigned d;
        asm("v_pk_mad_i16 %0, %1, %2, %3"
            : "=v"(d) : "v"(n2i[q]), "v"(jp), "v"(fj));
        asm("v_pk_min_i16 %0, %1, %2" : "=v"(acc[q]) : "v"(acc[q]), "v"(d));
      }
      jp += 0x10001u;
    }
    float hsum = 0.f, bsum = 0.f, hmax = 0.f;
    #pragma unroll
    for (int q = 0; q < 8; ++q) {
      const int xpr = g + 8 * q;
      const int xs2 = xpr * xpr;
      const int eT = (int)(short)(acc[q] & 0xFFFFu) + xs2;
      const int eL = (int)(short)(acc[q] >> 16) + xs2;
      const float tsd = sqrtf((float)eT) - sqrtf((float)eL);
      const float bnd = (float)((bndCol[xpr] >> zc) & 1ull);
      const float h = bnd * fabsf(tsd);
      hsum += h; bsum += bnd; hmax = fmaxf(hmax, h);
    }
    #pragma unroll
    for (int o = 32; o > 0; o >>= 1) {
      hsum += __shfl_down(hsum, o);
      bsum += __shfl_down(bsum, o);
      hmax = fmaxf(hmax, __shfl_down(hmax, o));
    }
    const int w = t >> 6;
    if ((t & 63) == 0) { redS[w] = hsum; redB[w] = bsum; redM[w] = hmax; }
  }
  __syncthreads();

  // ---- per-block partials + last-block final reduction ----
  float* part = (float*)((char*)wsv + PART_OFF);
  int* ctr = (int*)((char*)wsv + CTR_OFF);
  if (t == 0) {
    float s = 0.f, bs = 0.f, mx = 0.f;
    #pragma unroll
    for (int i = 0; i < 8; ++i) {
      s += redS[i]; bs += redB[i]; mx = fmaxf(mx, redM[i]);
    }
    float* pp = part + (size_t)bid * 8;
    pp[0] = s; pp[1] = bs; pp[2] = mx;
    __threadfence();
    const int old = atomicAdd(&ctr[0], 1);
    lastFlag = (old == 255) ? 1 : 0;
  }
  __syncthreads();
  if (lastFlag) {
    __threadfence();  // acquire other blocks' partials
    float s = 0.f, bs = 0.f, mx = 0.f;
    if (t < 256) {
      const float* pp = part + (size_t)t * 8;
      s = pp[0]; bs = pp[1]; mx = pp[2];
    }
    #pragma unroll
    for (int o = 32; o > 0; o >>= 1) {
      s += __shfl_down(s, o);
      bs += __shfl_down(bs, o);
      mx = fmaxf(mx, __shfl_down(mx, o));
    }
    __syncthreads();
    if ((t & 63) == 0 && t < 256) {
      redS[t >> 6] = s; redB[t >> 6] = bs; redM[t >> 6] = mx;
    }
    __syncthreads();
    if (t == 0) {
      // partials p<128 are m=0: h_outer + bnd2; p>=128: h_inner + bnd1
      const float s_ho = redS[0] + redS[1], b2 = redB[0] + redB[1];
      const float mho = fmaxf(redM[0], redM[1]);
      const float s_hi = redS[2] + redS[3], b1 = redB[2] + redB[3];
      const float mhi = fmaxf(redM[2], redM[3]);
      const float him = s_hi / b1;
      const float hom = s_ho / b2;
      out[0] = him;
      out[1] = mhi;
      out[2] = hom;
      out[3] = mho;
      out[4] = (him - 2.f) * (him - 2.f) + (hom - 2.f) * (hom - 2.f);
    }
  }
}

extern "C" void kernel_launch(void* const* d_in, const int* in_sizes, int n_in,
                              void* d_out, int out_size, void* d_ws,
                              size_t ws_size, hipStream_t stream) {
  (void)in_sizes; (void)n_in; (void)out_size; (void)ws_size;
  const int* mmap = (const int*)d_in[0];
  float* out = (float*)d_out;

  build_bits<<<128, 512, 0, stream>>>(mmap, d_ws);
  edt_all<<<256, 512, 0, stream>>>(d_ws, out);
}